// Round 1
// baseline (196.200 us; speedup 1.0000x reference)
//
#include <hip/hip_runtime.h>
#include <math.h>

// Problem constants
#define B_   64
#define T_   512
#define D_   96
#define TY_  512
#define H_   4
#define DK_  32
#define E_   128
#define P_   2
#define L_   64
#define HID_ 128

// Workspace layout (float offsets)
#define WS_W2Q   0         // 1024  : fused k_w * q / sqrt(32)  [e][hp]
#define WS_BQ    1024      // 8     : fused k_b * q / sqrt(32)  [hp]
#define WS_OB2   1032      // 64    : ob + const-half of ow     [l]
#define WS_WEXP  2048      // B*T*8 = 262144 : exp(s - max)     [(b,t)][hp]
#define WS_PN    264192    // 64*4*8*96 = 196608 : partial numerators
#define WS_PD    460800    // 196608 : partial denominators
#define WS_AB    657408    // 64*2*128 = 16384 : decoder a0/a1

// ---------------------------------------------------------------------------
// Kernel P: tiny precompute (1 block, 256 threads)
//   qm[p,e'] = query[p,:] @ q_w + q_b
//   w2q[e,hp] = sum_dk k_w[e, h*32+dk] * qm[p, h*32+dk] / sqrt(32)
//   bq[hp]    = sum_dk k_b[h*32+dk]    * qm[p, h*32+dk] / sqrt(32)
//   ob2[l]    = ob[l] + sum_{h,j} ow[(h*192+96+j)*64 + l]   (xa second half == 1)
// ---------------------------------------------------------------------------
__global__ __launch_bounds__(256) void kprep(
    const float* __restrict__ query, const float* __restrict__ q_w,
    const float* __restrict__ q_b,   const float* __restrict__ k_w,
    const float* __restrict__ k_b,   const float* __restrict__ ow,
    const float* __restrict__ ob,    float* __restrict__ ws)
{
    __shared__ float qm[P_ * E_];
    const int tid = threadIdx.x;
    {
        int p = tid >> 7, ep = tid & 127;
        float acc = q_b[ep];
        for (int e = 0; e < E_; ++e)
            acc += query[p * E_ + e] * q_w[e * E_ + ep];
        qm[p * E_ + ep] = acc;
    }
    __syncthreads();
    const float rs = 0.17677669529663687f;  // 1/sqrt(32)
    for (int idx = tid; idx < E_ * 8; idx += 256) {
        int e = idx >> 3, hp = idx & 7, h = hp >> 1, p = hp & 1;
        float acc = 0.f;
        #pragma unroll
        for (int dk = 0; dk < DK_; ++dk)
            acc += k_w[e * E_ + h * DK_ + dk] * qm[p * E_ + h * DK_ + dk];
        ws[WS_W2Q + idx] = acc * rs;
    }
    if (tid < 8) {
        int hp = tid, h = hp >> 1, p = hp & 1;
        float acc = 0.f;
        #pragma unroll
        for (int dk = 0; dk < DK_; ++dk)
            acc += k_b[h * DK_ + dk] * qm[p * E_ + h * DK_ + dk];
        ws[WS_BQ + hp] = acc * rs;
    }
    if (tid < L_) {
        float acc = ob[tid];
        for (int h = 0; h < H_; ++h)
            for (int j = 0; j < D_; ++j)
                acc += ow[(h * 2 * D_ + D_ + j) * L_ + tid];
        ws[WS_OB2 + tid] = acc;
    }
}

// ---------------------------------------------------------------------------
// Kernel S: scores + per-(b,hp) max + exp weights. One block per batch b.
//   emb[e] = ts*te_w[e]+te_b[e]; sin if e%4==0
//   s[t,hp] = emb . w2q[:,hp] + bq[hp];  wexp = exp(s - max_t s)
// ---------------------------------------------------------------------------
__global__ __launch_bounds__(256) void kscores(
    const float* __restrict__ tsteps, const float* __restrict__ te_w,
    const float* __restrict__ te_b,   float* __restrict__ ws)
{
    __shared__ float w2q_s[E_ * 8];
    __shared__ float tw_s[E_], tb_s[E_], bq_s[8];
    __shared__ float wred[4 * 8];
    __shared__ float smax[8];
    const int tid = threadIdx.x, b = blockIdx.x;

    for (int i = tid; i < E_ * 8; i += 256) w2q_s[i] = ws[WS_W2Q + i];
    if (tid < E_) { tw_s[tid] = te_w[tid]; tb_s[tid] = te_b[tid]; }
    if (tid < 8)  bq_s[tid] = ws[WS_BQ + tid];
    __syncthreads();

    float s[2][8];
    for (int i = 0; i < 2; ++i) {
        int t = tid + i * 256;
        float tv = tsteps[b * T_ + t];
        float acc[8] = {0.f, 0.f, 0.f, 0.f, 0.f, 0.f, 0.f, 0.f};
        for (int e = 0; e < E_; ++e) {
            float v = tv * tw_s[e] + tb_s[e];
            if ((e & 3) == 0) v = sinf(v);
            #pragma unroll
            for (int hp = 0; hp < 8; ++hp) acc[hp] += v * w2q_s[e * 8 + hp];
        }
        #pragma unroll
        for (int hp = 0; hp < 8; ++hp) s[i][hp] = acc[hp] + bq_s[hp];
    }

    // block max over t per hp
    float lm[8];
    #pragma unroll
    for (int hp = 0; hp < 8; ++hp) lm[hp] = fmaxf(s[0][hp], s[1][hp]);
    #pragma unroll
    for (int off = 32; off > 0; off >>= 1) {
        #pragma unroll
        for (int hp = 0; hp < 8; ++hp)
            lm[hp] = fmaxf(lm[hp], __shfl_down(lm[hp], off));
    }
    int lane = tid & 63, wv = tid >> 6;
    if (lane == 0) {
        #pragma unroll
        for (int hp = 0; hp < 8; ++hp) wred[wv * 8 + hp] = lm[hp];
    }
    __syncthreads();
    if (tid < 8) {
        float m = wred[tid];
        for (int w = 1; w < 4; ++w) m = fmaxf(m, wred[w * 8 + tid]);
        smax[tid] = m;
    }
    __syncthreads();

    for (int i = 0; i < 2; ++i) {
        int t = tid + i * 256;
        float4 v0, v1;
        v0.x = expf(s[i][0] - smax[0]); v0.y = expf(s[i][1] - smax[1]);
        v0.z = expf(s[i][2] - smax[2]); v0.w = expf(s[i][3] - smax[3]);
        v1.x = expf(s[i][4] - smax[4]); v1.y = expf(s[i][5] - smax[5]);
        v1.z = expf(s[i][6] - smax[6]); v1.w = expf(s[i][7] - smax[7]);
        float* dst = ws + WS_WEXP + ((size_t)(b * T_ + t)) * 8;
        *(float4*)dst = v0;
        *(float4*)(dst + 4) = v1;
    }
}

// ---------------------------------------------------------------------------
// Kernel A1: attention-pool partials over t-chunks of 128.
// grid (4 chunks, 64 batches), 256 threads: fid = tid&127 (f<96), slice=tid>>7
//   num[hp,f] += w[t,hp]*M*X ; den[hp,f] += w[t,hp]*M
// ---------------------------------------------------------------------------
__global__ __launch_bounds__(256) void kpool(
    const float* __restrict__ X, const float* __restrict__ M,
    float* __restrict__ ws)
{
    const int c = blockIdx.x, b = blockIdx.y, tid = threadIdx.x;
    __shared__ float w_s[128 * 8];
    __shared__ float red[96 * 17];  // stride 17 to dodge bank conflicts

    {   // stage this chunk's exp-weights: 1024 floats = 256 float4
        const float4* src = (const float4*)(ws + WS_WEXP + ((size_t)(b * T_ + c * 128)) * 8);
        ((float4*)w_s)[tid] = src[tid];
    }
    __syncthreads();

    const int fid = tid & 127, slice = tid >> 7;
    float num[8] = {0.f, 0.f, 0.f, 0.f, 0.f, 0.f, 0.f, 0.f};
    float den[8] = {0.f, 0.f, 0.f, 0.f, 0.f, 0.f, 0.f, 0.f};
    if (fid < 96) {
        for (int i = 0; i < 64; ++i) {
            int tl = slice + 2 * i;
            size_t base = ((size_t)(b * T_ + c * 128 + tl)) * D_ + fid;
            float m = M[base], x = X[base];
            float mx = m * x;
            const float* wr = w_s + tl * 8;
            #pragma unroll
            for (int hp = 0; hp < 8; ++hp) {
                num[hp] += wr[hp] * mx;
                den[hp] += wr[hp] * m;
            }
        }
    }
    __syncthreads();
    if (slice == 1 && fid < 96) {
        #pragma unroll
        for (int hp = 0; hp < 8; ++hp) {
            red[fid * 17 + hp] = num[hp];
            red[fid * 17 + 8 + hp] = den[hp];
        }
    }
    __syncthreads();
    if (slice == 0 && fid < 96) {
        float* pN = ws + WS_PN + ((size_t)((b * 4 + c) * 8)) * 96;
        float* pD = ws + WS_PD + ((size_t)((b * 4 + c) * 8)) * 96;
        #pragma unroll
        for (int hp = 0; hp < 8; ++hp) {
            pN[hp * 96 + fid] = num[hp] + red[fid * 17 + hp];
            pD[hp * 96 + fid] = den[hp] + red[fid * 17 + 8 + hp];
        }
    }
}

// ---------------------------------------------------------------------------
// Kernel A2: reduce partials -> xa -> coeffs -> decoder a0/a1. One block per b.
//   coeffs[p,l] = sum_{h,f<96} xa[h*2+p,f] * ow[(h*192+f)*64+l] + ob2[l]
//   a0[j] = b1[j] + c0 . w1[:,j] ; a1[j] = c1 . w1[:,j]
// ---------------------------------------------------------------------------
__global__ __launch_bounds__(128) void kcoef(
    const float* __restrict__ ow, const float* __restrict__ w1,
    const float* __restrict__ b1, float* __restrict__ ws)
{
    const int b = blockIdx.x, tid = threadIdx.x;  // 128 threads
    __shared__ float xa_s[8 * 96];
    __shared__ float cf_s[2 * 64];

    for (int flat = tid; flat < 8 * 96; flat += 128) {
        int hp = flat / 96, f = flat - hp * 96;
        float n = 0.f, d = 0.f;
        #pragma unroll
        for (int c = 0; c < 4; ++c) {
            n += ws[WS_PN + ((size_t)((b * 4 + c) * 8 + hp)) * 96 + f];
            d += ws[WS_PD + ((size_t)((b * 4 + c) * 8 + hp)) * 96 + f];
        }
        xa_s[flat] = n / d;
    }
    __syncthreads();
    {
        int p = tid >> 6, l = tid & 63;
        float acc = ws[WS_OB2 + l];
        for (int h = 0; h < 4; ++h) {
            const float* xr = xa_s + (h * 2 + p) * 96;
            const float* owr = ow + (size_t)(h * 192) * 64 + l;
            for (int f = 0; f < 96; ++f)
                acc += xr[f] * owr[(size_t)f * 64];
        }
        cf_s[p * 64 + l] = acc;
    }
    __syncthreads();
    {
        int j = tid;
        float a0 = b1[j], a1 = 0.f;
        for (int l = 0; l < 64; ++l) {
            float wv = w1[l * 128 + j];
            a0 += cf_s[l] * wv;
            a1 += cf_s[64 + l] * wv;
        }
        ws[WS_AB + b * 256 + j] = a0;
        ws[WS_AB + b * 256 + 128 + j] = a1;
    }
}

// ---------------------------------------------------------------------------
// Kernel D: decoder. Block = 64 positions (one b), 256 threads.
//   h[j,pos] = relu(a0[j] + y[pos]*a1[j])   (staged in LDS, 32 KB)
//   out[pos,d] = sum_j h[j,pos]*w2[j,d] + b2[d]   (4 pos x 6 d per thread)
// ---------------------------------------------------------------------------
__global__ __launch_bounds__(256) void kdec(
    const float* __restrict__ yts, const float* __restrict__ w2,
    const float* __restrict__ b2,  const float* __restrict__ ws,
    float* __restrict__ out)
{
    __shared__ float h_s[HID_ * 64];
    __shared__ float y_s[64];
    __shared__ float a0_s[HID_], a1_s[HID_];
    const int tid = threadIdx.x;
    const int posb = blockIdx.x * 64;   // flat position base (b*512 + ty0)
    const int b = posb >> 9;

    if (tid < 64) y_s[tid] = yts[posb + tid];
    if (tid >= 64 && tid < 192) {
        int j = tid - 64;
        a0_s[j] = ws[WS_AB + b * 256 + j];
        a1_s[j] = ws[WS_AB + b * 256 + 128 + j];
    }
    __syncthreads();

    #pragma unroll 4
    for (int r = 0; r < 32; ++r) {
        int flat = r * 256 + tid;       // = j*64 + pos
        int j = flat >> 6, pos = flat & 63;
        h_s[flat] = fmaxf(0.f, a0_s[j] + y_s[pos] * a1_s[j]);
    }
    __syncthreads();

    const int pg = tid >> 4, dg = tid & 15;
    const int p0 = pg * 4, d0 = dg * 6;
    float acc[4][6];
    #pragma unroll
    for (int pp = 0; pp < 4; ++pp)
        #pragma unroll
        for (int dd = 0; dd < 6; ++dd) acc[pp][dd] = 0.f;

    for (int j = 0; j < HID_; ++j) {
        float4 h4 = *(const float4*)&h_s[j * 64 + p0];
        const float* wr = w2 + j * D_ + d0;
        float wv[6];
        #pragma unroll
        for (int dd = 0; dd < 6; ++dd) wv[dd] = wr[dd];
        const float hv[4] = {h4.x, h4.y, h4.z, h4.w};
        #pragma unroll
        for (int pp = 0; pp < 4; ++pp)
            #pragma unroll
            for (int dd = 0; dd < 6; ++dd)
                acc[pp][dd] += hv[pp] * wv[dd];
    }

    float bv[6];
    #pragma unroll
    for (int dd = 0; dd < 6; ++dd) bv[dd] = b2[d0 + dd];
    #pragma unroll
    for (int pp = 0; pp < 4; ++pp) {
        size_t ob = ((size_t)(posb + p0 + pp)) * D_ + d0;
        #pragma unroll
        for (int dd = 0; dd < 6; ++dd) out[ob + dd] = acc[pp][dd] + bv[dd];
    }
}

// ---------------------------------------------------------------------------
extern "C" void kernel_launch(void* const* d_in, const int* in_sizes, int n_in,
                              void* d_out, int out_size, void* d_ws, size_t ws_size,
                              hipStream_t stream)
{
    const float* timesteps = (const float*)d_in[0];
    const float* X         = (const float*)d_in[1];
    const float* M         = (const float*)d_in[2];
    const float* yts       = (const float*)d_in[3];
    const float* te_w      = (const float*)d_in[4];
    const float* te_b      = (const float*)d_in[5];
    const float* query     = (const float*)d_in[6];
    const float* q_w       = (const float*)d_in[7];
    const float* q_b       = (const float*)d_in[8];
    const float* k_w       = (const float*)d_in[9];
    const float* k_b       = (const float*)d_in[10];
    const float* ow        = (const float*)d_in[11];
    const float* ob        = (const float*)d_in[12];
    const float* w1        = (const float*)d_in[13];
    const float* b1        = (const float*)d_in[14];
    const float* w2        = (const float*)d_in[15];
    const float* b2        = (const float*)d_in[16];
    float* out = (float*)d_out;
    float* ws  = (float*)d_ws;

    kprep<<<1, 256, 0, stream>>>(query, q_w, q_b, k_w, k_b, ow, ob, ws);
    kscores<<<B_, 256, 0, stream>>>(timesteps, te_w, te_b, ws);
    kpool<<<dim3(4, B_), 256, 0, stream>>>(X, M, ws);
    kcoef<<<B_, 128, 0, stream>>>(ow, w1, b1, ws);
    kdec<<<(B_ * TY_) / 64, 256, 0, stream>>>(yts, w2, b2, ws, out);
}

// Round 2
// 164.265 us; speedup vs baseline: 1.1944x; 1.1944x over previous
//
#include <hip/hip_runtime.h>
#include <math.h>

// Problem constants
#define B_   64
#define T_   512
#define D_   96
#define TY_  512
#define H_   4
#define DK_  32
#define E_   128
#define P_   2
#define L_   64
#define HID_ 128

// Workspace layout (float offsets)
#define WS_W2Q   0         // 1024  : fused k_w * q / sqrt(32)  [e][hp]
#define WS_BQ    1024      // 8     : fused k_b * q / sqrt(32)  [hp]
#define WS_OB2   1056      // 64    : ob + const-half of ow     [l]
#define WS_PN    2048      // 64b*8c*8hp*96f = 393216 : partial numerators
#define WS_PD    395264    // 393216 : partial denominators
#define WS_AB    788480    // 64*2*128 = 16384 : decoder a0/a1

// ---------------------------------------------------------------------------
// Kernel P: precompute, 2 blocks x 256 threads.
// block 0: qm[p,e'] = query[p,:] @ q_w + q_b
//          w2q[e,hp] = sum_dk k_w[e,h*32+dk]*qm[p,h*32+dk]/sqrt(32)
//          bq[hp]    = sum_dk k_b[h*32+dk]  *qm[p,h*32+dk]/sqrt(32)
// block 1: ob2[l] = ob[l] + sum_{h,j} ow[(h*192+96+j)*64+l]  (xa 2nd half == 1)
// ---------------------------------------------------------------------------
__global__ __launch_bounds__(256) void kprep(
    const float* __restrict__ query, const float* __restrict__ q_w,
    const float* __restrict__ q_b,   const float* __restrict__ k_w,
    const float* __restrict__ k_b,   const float* __restrict__ ow,
    const float* __restrict__ ob,    float* __restrict__ ws)
{
    const int tid = threadIdx.x;
    if (blockIdx.x == 0) {
        __shared__ float qm[P_ * E_];
        {
            int p = tid >> 7, ep = tid & 127;
            float acc = q_b[ep];
            #pragma unroll 4
            for (int e = 0; e < E_; ++e)
                acc += query[p * E_ + e] * q_w[e * E_ + ep];
            qm[p * E_ + ep] = acc;
        }
        __syncthreads();
        const float rs = 0.17677669529663687f;  // 1/sqrt(32)
        for (int idx = tid; idx < E_ * 8; idx += 256) {
            int e = idx >> 3, hp = idx & 7, h = hp >> 1, p = hp & 1;
            float acc = 0.f;
            #pragma unroll
            for (int dk = 0; dk < DK_; ++dk)
                acc += k_w[e * E_ + h * DK_ + dk] * qm[p * E_ + h * DK_ + dk];
            ws[WS_W2Q + idx] = acc * rs;
        }
        if (tid < 8) {
            int hp = tid, h = hp >> 1, p = hp & 1;
            float acc = 0.f;
            #pragma unroll
            for (int dk = 0; dk < DK_; ++dk)
                acc += k_b[h * DK_ + dk] * qm[p * E_ + h * DK_ + dk];
            ws[WS_BQ + hp] = acc * rs;
        }
    } else {
        // ob2: 4 slices (one per h) x 64 l
        __shared__ float obred[4][64];
        int l = tid & 63, sl = tid >> 6;
        float acc = 0.f;
        #pragma unroll 4
        for (int j = 0; j < D_; ++j)
            acc += ow[(size_t)(sl * 2 * D_ + D_ + j) * L_ + l];
        obred[sl][l] = acc;
        __syncthreads();
        if (sl == 0)
            ws[WS_OB2 + l] = ob[l] + obred[0][l] + obred[1][l] + obred[2][l] + obred[3][l];
    }
}

// ---------------------------------------------------------------------------
// Kernel SP (fused scores + exp + pool): grid (8 t-chunks, 64 b), 256 thr.
// Phase A: w[t,hp] = exp(emb(t) . w2q[:,hp] + bq[hp])   (no max-sub: |s|<~20)
// Phase B: num[hp,f] += w*M*X ; den[hp,f] += w*M  over the 64-t chunk
// ---------------------------------------------------------------------------
__global__ __launch_bounds__(256) void kspool(
    const float* __restrict__ tsteps, const float* __restrict__ te_w,
    const float* __restrict__ te_b,   const float* __restrict__ X,
    const float* __restrict__ M,      float* __restrict__ ws)
{
    const int c = blockIdx.x, b = blockIdx.y, tid = threadIdx.x;
    __shared__ float w2q_s[E_ * 8];
    __shared__ float tw_s[E_], tb_s[E_], bq_s[8];
    __shared__ float w_s[64 * 8];
    __shared__ float red[96 * 17];  // stride 17: no bank conflicts

    #pragma unroll
    for (int i = 0; i < 4; ++i) w2q_s[tid + i * 256] = ws[WS_W2Q + tid + i * 256];
    if (tid < E_) { tw_s[tid] = te_w[tid]; tb_s[tid] = te_b[tid]; }
    if (tid < 8)  bq_s[tid] = ws[WS_BQ + tid];
    __syncthreads();

    // ---- Phase A: thread = (t in chunk, hp-pair) ----
    {
        const int t = tid & 63, hpg = tid >> 6, hp0 = hpg * 2;
        const float tv = tsteps[b * T_ + c * 64 + t];
        float a0 = 0.f, a1 = 0.f;
        #pragma unroll 4
        for (int e = 0; e < E_; ++e) {
            float v = tv * tw_s[e] + tb_s[e];
            if ((e & 3) == 0) v = __sinf(v);
            float2 w = *(const float2*)&w2q_s[e * 8 + hp0];
            a0 += v * w.x;
            a1 += v * w.y;
        }
        w_s[t * 8 + hp0]     = __expf(a0 + bq_s[hp0]);
        w_s[t * 8 + hp0 + 1] = __expf(a1 + bq_s[hp0 + 1]);
    }
    __syncthreads();

    // ---- Phase B: 2 t-slices x 128 fid (96 active) ----
    const int fid = tid & 127, slice = tid >> 7;
    float num[8] = {0.f, 0.f, 0.f, 0.f, 0.f, 0.f, 0.f, 0.f};
    float den[8] = {0.f, 0.f, 0.f, 0.f, 0.f, 0.f, 0.f, 0.f};
    if (fid < 96) {
        #pragma unroll 4
        for (int i = 0; i < 32; ++i) {
            int tl = slice + 2 * i;
            size_t base = ((size_t)(b * T_ + c * 64 + tl)) * D_ + fid;
            float m = M[base], x = X[base];
            float mx = m * x;
            const float* wr = w_s + tl * 8;
            #pragma unroll
            for (int hp = 0; hp < 8; ++hp) {
                num[hp] += wr[hp] * mx;
                den[hp] += wr[hp] * m;
            }
        }
    }
    __syncthreads();
    if (slice == 1 && fid < 96) {
        #pragma unroll
        for (int hp = 0; hp < 8; ++hp) {
            red[fid * 17 + hp]     = num[hp];
            red[fid * 17 + 8 + hp] = den[hp];
        }
    }
    __syncthreads();
    if (slice == 0 && fid < 96) {
        float* pN = ws + WS_PN + ((size_t)((b * 8 + c) * 8)) * 96;
        float* pD = ws + WS_PD + ((size_t)((b * 8 + c) * 8)) * 96;
        #pragma unroll
        for (int hp = 0; hp < 8; ++hp) {
            pN[hp * 96 + fid] = num[hp] + red[fid * 17 + hp];
            pD[hp * 96 + fid] = den[hp] + red[fid * 17 + 8 + hp];
        }
    }
}

// ---------------------------------------------------------------------------
// Kernel A2: reduce partials -> xa -> coeffs -> decoder a0/a1. 64 b x 256 thr.
// ---------------------------------------------------------------------------
__global__ __launch_bounds__(256) void kcoef(
    const float* __restrict__ ow, const float* __restrict__ w1,
    const float* __restrict__ b1, float* __restrict__ ws)
{
    const int b = blockIdx.x, tid = threadIdx.x;
    __shared__ float xa_s[8 * 96];
    __shared__ float cf_part[2 * 128];
    __shared__ float cf_s[2 * 64];

    for (int flat = tid; flat < 8 * 96; flat += 256) {
        int hp = flat / 96, f = flat - hp * 96;
        float n = 0.f, d = 0.f;
        #pragma unroll
        for (int c = 0; c < 8; ++c) {
            n += ws[WS_PN + ((size_t)((b * 8 + c) * 8 + hp)) * 96 + f];
            d += ws[WS_PD + ((size_t)((b * 8 + c) * 8 + hp)) * 96 + f];
        }
        xa_s[flat] = n / d;
    }
    __syncthreads();
    {   // coeffs[p,l], h-loop split across hh = tid>>7
        int hh = tid >> 7, rem = tid & 127, p = rem >> 6, l = rem & 63;
        float acc = (hh == 0) ? ws[WS_OB2 + l] : 0.f;
        #pragma unroll
        for (int hi = 0; hi < 2; ++hi) {
            int h = hh * 2 + hi;
            const float* xr = xa_s + (h * 2 + p) * 96;
            const float* owr = ow + (size_t)(h * 2 * D_) * L_ + l;
            #pragma unroll 4
            for (int f = 0; f < 96; ++f)
                acc += xr[f] * owr[(size_t)f * L_];
        }
        cf_part[hh * 128 + rem] = acc;
    }
    __syncthreads();
    if (tid < 128) cf_s[tid] = cf_part[tid] + cf_part[128 + tid];
    __syncthreads();
    if (tid < 128) {
        int j = tid;
        float a0 = b1[j], a1 = 0.f;
        #pragma unroll 4
        for (int l = 0; l < 64; ++l) {
            float wv = w1[l * HID_ + j];
            a0 += cf_s[l] * wv;
            a1 += cf_s[64 + l] * wv;
        }
        ws[WS_AB + b * 256 + j] = a0;
        ws[WS_AB + b * 256 + 128 + j] = a1;
    }
}

// ---------------------------------------------------------------------------
// Kernel D: decoder. Block = 64 positions (one b), 256 threads.
//   h[j,pos] = relu(a0[j] + y[pos]*a1[j])   staged in LDS (32 KB)
//   out[pos,d] = sum_j h[j,pos]*w2[j,d] + b2[d]   (4 pos x 6 d per thread)
// ---------------------------------------------------------------------------
__global__ __launch_bounds__(256) void kdec(
    const float* __restrict__ yts, const float* __restrict__ w2,
    const float* __restrict__ b2,  const float* __restrict__ ws,
    float* __restrict__ out)
{
    __shared__ float h_s[HID_ * 64];
    __shared__ float y_s[64];
    __shared__ float a0_s[HID_], a1_s[HID_];
    const int tid = threadIdx.x;
    const int posb = blockIdx.x * 64;   // flat position base (b*512 + ty0)
    const int b = posb >> 9;

    if (tid < 64) y_s[tid] = yts[posb + tid];
    if (tid >= 64 && tid < 192) {
        int j = tid - 64;
        a0_s[j] = ws[WS_AB + b * 256 + j];
        a1_s[j] = ws[WS_AB + b * 256 + 128 + j];
    }
    __syncthreads();

    #pragma unroll 4
    for (int r = 0; r < 32; ++r) {
        int flat = r * 256 + tid;       // = j*64 + pos
        int j = flat >> 6, pos = flat & 63;
        h_s[flat] = fmaxf(0.f, a0_s[j] + y_s[pos] * a1_s[j]);
    }
    __syncthreads();

    const int pg = tid >> 4, dg = tid & 15;
    const int p0 = pg * 4, d0 = dg * 6;
    float acc[4][6];
    #pragma unroll
    for (int pp = 0; pp < 4; ++pp)
        #pragma unroll
        for (int dd = 0; dd < 6; ++dd) acc[pp][dd] = 0.f;

    #pragma unroll 2
    for (int j = 0; j < HID_; ++j) {
        float4 h4 = *(const float4*)&h_s[j * 64 + p0];
        const float* wr = w2 + j * D_ + d0;
        float wv[6];
        #pragma unroll
        for (int dd = 0; dd < 6; ++dd) wv[dd] = wr[dd];
        const float hv[4] = {h4.x, h4.y, h4.z, h4.w};
        #pragma unroll
        for (int pp = 0; pp < 4; ++pp)
            #pragma unroll
            for (int dd = 0; dd < 6; ++dd)
                acc[pp][dd] += hv[pp] * wv[dd];
    }

    float bv[6];
    #pragma unroll
    for (int dd = 0; dd < 6; ++dd) bv[dd] = b2[d0 + dd];
    #pragma unroll
    for (int pp = 0; pp < 4; ++pp) {
        size_t ob = ((size_t)(posb + p0 + pp)) * D_ + d0;
        #pragma unroll
        for (int dd = 0; dd < 6; ++dd) out[ob + dd] = acc[pp][dd] + bv[dd];
    }
}

// ---------------------------------------------------------------------------
extern "C" void kernel_launch(void* const* d_in, const int* in_sizes, int n_in,
                              void* d_out, int out_size, void* d_ws, size_t ws_size,
                              hipStream_t stream)
{
    const float* timesteps = (const float*)d_in[0];
    const float* X         = (const float*)d_in[1];
    const float* M         = (const float*)d_in[2];
    const float* yts       = (const float*)d_in[3];
    const float* te_w      = (const float*)d_in[4];
    const float* te_b      = (const float*)d_in[5];
    const float* query     = (const float*)d_in[6];
    const float* q_w       = (const float*)d_in[7];
    const float* q_b       = (const float*)d_in[8];
    const float* k_w       = (const float*)d_in[9];
    const float* k_b       = (const float*)d_in[10];
    const float* ow        = (const float*)d_in[11];
    const float* ob        = (const float*)d_in[12];
    const float* w1        = (const float*)d_in[13];
    const float* b1        = (const float*)d_in[14];
    const float* w2        = (const float*)d_in[15];
    const float* b2        = (const float*)d_in[16];
    float* out = (float*)d_out;
    float* ws  = (float*)d_ws;

    kprep<<<2, 256, 0, stream>>>(query, q_w, q_b, k_w, k_b, ow, ob, ws);
    kspool<<<dim3(8, B_), 256, 0, stream>>>(timesteps, te_w, te_b, X, M, ws);
    kcoef<<<B_, 256, 0, stream>>>(ow, w1, b1, ws);
    kdec<<<(B_ * TY_) / 64, 256, 0, stream>>>(yts, w2, b2, ws, out);
}